// Round 4
// baseline (1242.614 us; speedup 1.0000x reference)
//
#include <hip/hip_runtime.h>
#include <stdint.h>

#define NPTS 8000
#define NBATCH 4
#define TOTALP (NBATCH * NPTS)
#define KSEL 32
#define CAND 4000  /* NPTS / 2 candidate-halves for the scan kernel */

typedef uint32_t u32;
typedef unsigned long long u64;

// ---------------- Kernel A: encoder + g1/g2 precompute ----------------
// feats = relu(x@ew1+eb1)@ew2+eb2 ; g1 = feats@f1w ; g2 = feats@f2w
__global__ __launch_bounds__(256) void encode_kernel(
    const float* __restrict__ x,
    const float* __restrict__ ew1, const float* __restrict__ eb1,
    const float* __restrict__ ew2, const float* __restrict__ eb2,
    const float* __restrict__ f1w, const float* __restrict__ f2w,
    float* __restrict__ g1, float* __restrict__ g2)
{
    __shared__ float sw1[9 * 64];
    __shared__ float sw2[64 * 64];
    __shared__ float sf1[64 * 64];
    __shared__ float sf2[64 * 64];
    __shared__ float sb1[64];
    __shared__ float sb2[64];
    __shared__ float shb[4][64];
    __shared__ float sfb[4][64];

    const int tid = threadIdx.x;
    for (int i = tid; i < 9 * 64; i += 256) sw1[i] = ew1[i];
    for (int i = tid; i < 64 * 64; i += 256) {
        sw2[i] = ew2[i]; sf1[i] = f1w[i]; sf2[i] = f2w[i];
    }
    if (tid < 64) { sb1[tid] = eb1[tid]; sb2[tid] = eb2[tid]; }
    __syncthreads();

    const int lane = tid & 63;
    const int w = tid >> 6;
    const int gw = blockIdx.x * 4 + w;
    const int nw = 256 * 4;  // grid fixed at 256 blocks

    #pragma unroll 1
    for (int it = 0; it < 32; ++it) {
        int p = gw + it * nw;
        int pc = p < TOTALP ? p : TOTALP - 1;
        const float* xp = x + (size_t)pc * 9;

        float acc = sb1[lane];
        #pragma unroll
        for (int i = 0; i < 9; ++i) acc = fmaf(xp[i], sw1[i * 64 + lane], acc);
        shb[w][lane] = fmaxf(acc, 0.f);
        __syncthreads();

        float fa = sb2[lane];
        #pragma unroll
        for (int c = 0; c < 64; ++c) fa = fmaf(shb[w][c], sw2[c * 64 + lane], fa);
        sfb[w][lane] = fa;
        __syncthreads();

        float a1 = 0.f, a2 = 0.f;
        #pragma unroll
        for (int c = 0; c < 64; ++c) {
            float fv = sfb[w][c];
            a1 = fmaf(fv, sf1[c * 64 + lane], a1);
            a2 = fmaf(fv, sf2[c * 64 + lane], a2);
        }
        if (p < TOTALP) {
            g1[(size_t)p * 64 + lane] = a1;
            g2[(size_t)p * 64 + lane] = a2;
        }
        __syncthreads();
    }
}

// ---------------- Kernel B: np-f32-replicating KNN scan (per half) --------
// Thread-per-query. Replicates the numpy reference's f32 arithmetic exactly:
//   n2   = rn(rn(x*x) + rn(y*y)) + rn(z*z)        (np.sum of 3: serial)
//   dot  = fma(z,bz, fma(y,by, rn(x*bx)))         (BLAS/einsum k-asc fma chain)
//   d    = rn_sub(rn_add(n2q, n2m), rn_mul(2,dot))
// Key = order-mapped f32 bits << 13 | idx  (tie-break = smallest index,
// matching lax.top_k stability). Per-half top-32 under THIS key, merged
// exactly in B2, IS the reference's top-32 if the metric matches — the
// metric is the only remaining degree of freedom.
__global__ __launch_bounds__(256) void knn_scan_kernel(
    const float* __restrict__ x, u64* __restrict__ keys)
{
    __shared__ float4 sc[CAND];
    const int b = blockIdx.z;
    const int half = blockIdx.y;
    const int c0 = half * CAND;
    const float* xb = x + (size_t)b * NPTS * 9;
    const int tid = threadIdx.x;

    for (int i = tid; i < CAND; i += 256) {
        const float* cp = xb + (size_t)(c0 + i) * 9;
        float cx = cp[0], cy = cp[1], cz = cp[2];
        float n2 = __fadd_rn(
            __fadd_rn(__fmul_rn(cx, cx), __fmul_rn(cy, cy)), __fmul_rn(cz, cz));
        sc[i] = make_float4(cx, cy, cz, n2);
    }
    __syncthreads();

    const int q = blockIdx.x * 256 + tid;
    const int qc = q < NPTS ? q : NPTS - 1;
    const float* qp = xb + (size_t)qc * 9;
    const float qx = qp[0], qy = qp[1], qz = qp[2];
    const float qn2 = __fadd_rn(
        __fadd_rn(__fmul_rn(qx, qx), __fmul_rn(qy, qy)), __fmul_rn(qz, qz));

    u64 sk[KSEL];
    #pragma unroll
    for (int i = 0; i < KSEL; ++i) sk[i] = ~0ULL;
    u64 thr = ~0ULL;
    u64 pd0 = 0, pd1 = 0, pd2 = 0, pd3 = 0;
    int pcnt = 0;

#define DRAIN()                                                         \
    do {                                                                \
        _Pragma("unroll")                                               \
        for (int j = 0; j < 4; ++j) {                                   \
            u64 nk = (j == 0) ? pd0 : (j == 1) ? pd1 : (j == 2) ? pd2 : pd3; \
            if (j >= pcnt) nk = ~0ULL;                                  \
            _Pragma("unroll")                                           \
            for (int t = 0; t < KSEL; ++t) {                            \
                u64 a = sk[t];                                          \
                bool lt = nk < a;                                       \
                sk[t] = lt ? nk : a;                                    \
                nk = lt ? a : nk;                                       \
            }                                                           \
        }                                                               \
        pcnt = 0;                                                       \
        thr = sk[KSEL - 1];                                             \
    } while (0)

    #pragma unroll 1
    for (int i = 0; i < CAND; ++i) {
        float4 c = sc[i];
        // np/BLAS rounding: fma chain over d ascending, first term plain mul
        float dot = fmaf(qz, c.z, fmaf(qy, c.y, __fmul_rn(qx, c.x)));
        float d = __fsub_rn(__fadd_rn(qn2, c.w), __fmul_rn(2.0f, dot));
        // order-preserving f32 -> u32 (handles negative d from cancellation)
        u32 db = __float_as_uint(d);
        db = (db & 0x80000000u) ? ~db : (db | 0x80000000u);
        u64 key = (((u64)db) << 13) | (u64)(c0 + i);
        bool take = key < thr;
        pd0 = (take && pcnt == 0) ? key : pd0;
        pd1 = (take && pcnt == 1) ? key : pd1;
        pd2 = (take && pcnt == 2) ? key : pd2;
        pd3 = (take && pcnt == 3) ? key : pd3;
        pcnt += (int)take;
        if (__any(pcnt == 4)) DRAIN();
    }
    DRAIN();
#undef DRAIN

    if (q < NPTS) {
        u64* kp = keys + ((size_t)(b * NPTS + q) * 2 + half) * KSEL;
        #pragma unroll
        for (int i = 0; i < KSEL; ++i) kp[i] = sk[i];
    }
}

// ---------------- Kernel B2: exact 64 -> 32 merge on the same keys -------
// Both halves ranked by the identical key, so the 32 smallest u64 keys of
// the union ARE the metric's top-32 (index tie-break consistent).
__global__ __launch_bounds__(256) void knn_merge_kernel(
    const u64* __restrict__ keys, int* __restrict__ idxo)
{
    int p = blockIdx.x * 256 + threadIdx.x;
    if (p >= TOTALP) return;
    const u64* kp = keys + (size_t)p * 2 * KSEL;

    u64 sk[KSEL];
    #pragma unroll
    for (int t = 0; t < KSEL; ++t) sk[t] = kp[t];
    #pragma unroll 1
    for (int t = 0; t < KSEL; ++t) {
        u64 nk = kp[KSEL + t];
        #pragma unroll
        for (int i = 0; i < KSEL; ++i) {
            u64 a = sk[i];
            bool lt = nk < a;
            sk[i] = lt ? nk : a;
            nk = lt ? a : nk;
        }
    }

    int* op = idxo + (size_t)p * KSEL;
    #pragma unroll
    for (int i = 0; i < KSEL; ++i) op[i] = (int)(sk[i] & 0x1FFFULL);
}

// ---------------- Kernel C: gather + edge + relu + maxpool (both fuses) ----
__global__ __launch_bounds__(256) void fuse_kernel(
    const float* __restrict__ g1, const float* __restrict__ g2,
    const int* __restrict__ idxo,
    const float* __restrict__ f1b, const float* __restrict__ f2b,
    float* __restrict__ fused)
{
    const int lane = threadIdx.x & 63;
    const int gw = (int)((blockIdx.x * 256 + threadIdx.x) >> 6);
    const int nw = 512 * 4;  // grid fixed at 512 blocks
    const float bias1 = f1b[lane];
    const float bias2 = f2b[lane];
    for (int p = gw; p < TOTALP; p += nw) {
        int b = p / NPTS;
        const int* mi = idxo + (size_t)p * KSEL;
        const float* G1 = g1 + (size_t)b * NPTS * 64;
        const float* G2 = g2 + (size_t)b * NPTS * 64;
        float base1 = bias1 - g1[(size_t)p * 64 + lane];
        float base2 = bias2 - g2[(size_t)p * 64 + lane];
        float a1 = 0.f, a2 = 0.f;
        #pragma unroll
        for (int k = 0; k < KSEL; ++k) {
            int j = mi[k];
            a1 = fmaxf(a1, G1[(size_t)j * 64 + lane] + base1);
            a2 = fmaxf(a2, G2[(size_t)j * 64 + lane] + base2);
        }
        fused[(size_t)p * 64 + lane] = a1 + a2;
    }
}

// ---------------- Kernel D: classifier MLP ----------------
__global__ __launch_bounds__(256) void cls_kernel(
    const float* __restrict__ fused,
    const float* __restrict__ cw1, const float* __restrict__ cb1,
    const float* __restrict__ cw2, const float* __restrict__ cb2,
    float* __restrict__ out)
{
    __shared__ float sw1[64 * 32];
    __shared__ float sw2[32 * 13];
    __shared__ float sb1[32];
    __shared__ float sb2[13];
    const int tid = threadIdx.x;
    for (int i = tid; i < 64 * 32; i += 256) sw1[i] = cw1[i];
    for (int i = tid; i < 32 * 13; i += 256) sw2[i] = cw2[i];
    if (tid < 32) sb1[tid] = cb1[tid];
    if (tid < 13) sb2[tid] = cb2[tid];
    __syncthreads();

    int p = blockIdx.x * 256 + tid;
    if (p >= TOTALP) return;

    float fu[64];
    const float4* fp = (const float4*)(fused + (size_t)p * 64);
    #pragma unroll
    for (int i = 0; i < 16; ++i) {
        float4 v = fp[i];
        fu[i * 4 + 0] = v.x; fu[i * 4 + 1] = v.y;
        fu[i * 4 + 2] = v.z; fu[i * 4 + 3] = v.w;
    }
    float h[32];
    #pragma unroll
    for (int j = 0; j < 32; j += 4) {
        float ax = sb1[j], ay = sb1[j + 1], az = sb1[j + 2], aw = sb1[j + 3];
        #pragma unroll
        for (int c = 0; c < 64; ++c) {
            float4 wv = *(const float4*)&sw1[c * 32 + j];
            ax = fmaf(fu[c], wv.x, ax);
            ay = fmaf(fu[c], wv.y, ay);
            az = fmaf(fu[c], wv.z, az);
            aw = fmaf(fu[c], wv.w, aw);
        }
        h[j] = fmaxf(ax, 0.f); h[j + 1] = fmaxf(ay, 0.f);
        h[j + 2] = fmaxf(az, 0.f); h[j + 3] = fmaxf(aw, 0.f);
    }
    float* op = out + (size_t)p * 13;
    #pragma unroll
    for (int o = 0; o < 13; ++o) {
        float acc = sb2[o];
        #pragma unroll
        for (int j = 0; j < 32; ++j) acc = fmaf(h[j], sw2[j * 13 + o], acc);
        op[o] = acc;
    }
}

extern "C" void kernel_launch(void* const* d_in, const int* in_sizes, int n_in,
                              void* d_out, int out_size, void* d_ws, size_t ws_size,
                              hipStream_t stream)
{
    const float* x   = (const float*)d_in[0];
    const float* ew1 = (const float*)d_in[1];
    const float* eb1 = (const float*)d_in[2];
    const float* ew2 = (const float*)d_in[3];
    const float* eb2 = (const float*)d_in[4];
    const float* f1w = (const float*)d_in[5];
    const float* f1b = (const float*)d_in[6];
    const float* f2w = (const float*)d_in[7];
    const float* f2b = (const float*)d_in[8];
    const float* cw1 = (const float*)d_in[9];
    const float* cb1 = (const float*)d_in[10];
    const float* cw2 = (const float*)d_in[11];
    const float* cb2 = (const float*)d_in[12];
    float* out = (float*)d_out;

    // workspace layout (~36.9 MB): [g1 8.2M][g2 8.2M][keys 16.4M][idxo 4.1M]
    // 'fused' aliases 'keys' (keys are dead after knn_merge_kernel).
    float* g1   = (float*)d_ws;
    float* g2   = g1 + (size_t)TOTALP * 64;
    u64*  keys  = (u64*)(g2 + (size_t)TOTALP * 64);
    int*  idxo  = (int*)(keys + (size_t)TOTALP * 2 * KSEL);
    float* fused = (float*)keys;

    hipLaunchKernelGGL(encode_kernel, dim3(256), dim3(256), 0, stream,
                       x, ew1, eb1, ew2, eb2, f1w, f2w, g1, g2);
    hipLaunchKernelGGL(knn_scan_kernel, dim3(32, 2, NBATCH), dim3(256), 0, stream,
                       x, keys);
    hipLaunchKernelGGL(knn_merge_kernel, dim3(125), dim3(256), 0, stream,
                       keys, idxo);
    hipLaunchKernelGGL(fuse_kernel, dim3(512), dim3(256), 0, stream,
                       g1, g2, idxo, f1b, f2b, fused);
    hipLaunchKernelGGL(cls_kernel, dim3(125), dim3(256), 0, stream,
                       fused, cw1, cb1, cw2, cb2, out);
}